// Round 2
// baseline (2342.287 us; speedup 1.0000x reference)
//
#include <hip/hip_runtime.h>

// GAT (2-layer) on MI355X. Closed-form segment softmax:
// alpha in {+t,-t}; per-src: p = #pos edges, deg = out-degree.
// p>0: w = (flag?1:e^{-2t}) / (p + (deg-p)e^{-2t});  p==0: w = 1/deg.
// NOTE: edge_index arrives as int32 (harness converts integer inputs to int).
#define EXP_NEG2T 0.13533528323661270f  // exp(-2*1.0)

__global__ void zero_i32(int* __restrict__ p, int n) {
  int i = blockIdx.x * blockDim.x + threadIdx.x;
  if (i < n) p[i] = 0;
}

template <int D>
__global__ void init_bias_k(float* __restrict__ agg, const float* __restrict__ b, int N) {
  int i = blockIdx.x * blockDim.x + threadIdx.x;
  if (i < N * D) agg[i] = b[i & (D - 1)];
}

// h[N, DOUT] = (RELU_IN ? relu(x) : x)[N,64] @ W[DOUT,64]^T
// One row per thread; W staged in LDS (reads are wave-uniform broadcasts).
template <int DOUT, bool RELU_IN>
__global__ void gemm_k(const float* __restrict__ x, const float* __restrict__ W,
                       float* __restrict__ h, int N) {
  __shared__ float Wl[DOUT * 64];
  for (int i = threadIdx.x; i < DOUT * 64; i += 256) Wl[i] = W[i];
  __syncthreads();
  int row = blockIdx.x * 256 + threadIdx.x;
  if (row >= N) return;
  const float4* xp = (const float4*)(x + (size_t)row * 64);
  float4 xr[16];
#pragma unroll
  for (int i = 0; i < 16; i++) {
    float4 v = xp[i];
    if (RELU_IN) {
      v.x = fmaxf(v.x, 0.f); v.y = fmaxf(v.y, 0.f);
      v.z = fmaxf(v.z, 0.f); v.w = fmaxf(v.w, 0.f);
    }
    xr[i] = v;
  }
  float* hp = h + (size_t)row * DOUT;
  for (int d = 0; d < DOUT; d++) {
    const float4* wp = (const float4*)(Wl + d * 64);
    float acc = 0.f;
#pragma unroll
    for (int i = 0; i < 16; i++) {
      float4 w = wp[i];
      acc = fmaf(xr[i].x, w.x, acc);
      acc = fmaf(xr[i].y, w.y, acc);
      acc = fmaf(xr[i].z, w.z, acc);
      acc = fmaf(xr[i].w, w.w, acc);
    }
    hp[d] = acc;
  }
}

// Per edge (including N appended self-loops): dot(h[dst],h[src]) sign ->
// flag byte; histogram pos[src] (and deg[src] on first layer only).
template <int D, bool COUNT_DEG>
__global__ void edge_alpha_k(const int* __restrict__ ei, const float* __restrict__ h,
                             unsigned char* __restrict__ flags, int* __restrict__ pos,
                             int* __restrict__ deg, int E, int N) {
  int e = blockIdx.x * blockDim.x + threadIdx.x;
  if (e >= E + N) return;
  int s, d;
  if (e < E) {
    s = ei[e];
    d = ei[E + e];
  } else {
    s = e - E; d = s;
  }
  const float4* hs = (const float4*)(h + (size_t)s * D);
  const float4* hd = (const float4*)(h + (size_t)d * D);
  float acc = 0.f;
#pragma unroll
  for (int i = 0; i < D / 4; i++) {
    float4 a = hs[i], b = hd[i];
    acc = fmaf(a.x, b.x, fmaf(a.y, b.y, fmaf(a.z, b.z, fmaf(a.w, b.w, acc))));
  }
  bool p = acc > 0.f;
  flags[e] = (unsigned char)p;
  if (COUNT_DEG) atomicAdd(deg + s, 1);
  if (p) atomicAdd(pos + s, 1);
}

// One thread per (edge, 4-channel group): agg[dst] += w * h[src].
template <int D>
__global__ void edge_scatter_k(const int* __restrict__ ei, const float* __restrict__ h,
                               const unsigned char* __restrict__ flags,
                               const int* __restrict__ pos, const int* __restrict__ deg,
                               float* __restrict__ agg, int E, int N) {
  const int V = D / 4;  // float4 groups per row (power of 2)
  long long tid = (long long)blockIdx.x * blockDim.x + threadIdx.x;
  long long total = (long long)(E + N) * V;
  if (tid >= total) return;
  int e = (int)(tid / V);
  int c = ((int)tid & (V - 1)) * 4;
  int s, d;
  if (e < E) {
    s = ei[e];
    d = ei[E + e];
  } else {
    s = e - E; d = s;
  }
  int p = pos[s], dg = deg[s];
  float w;
  if (p > 0) {
    float denom = (float)p + (float)(dg - p) * EXP_NEG2T;
    w = (flags[e] ? 1.0f : EXP_NEG2T) / denom;
  } else {
    w = 1.0f / (float)dg;
  }
  float4 hv = *(const float4*)(h + (size_t)s * D + c);
  float* o = agg + (size_t)d * D + c;
  atomicAdd(o + 0, w * hv.x);
  atomicAdd(o + 1, w * hv.y);
  atomicAdd(o + 2, w * hv.z);
  atomicAdd(o + 3, w * hv.w);
}

__global__ void logsoftmax16_k(const float* __restrict__ agg, float* __restrict__ out, int N) {
  int n = blockIdx.x * blockDim.x + threadIdx.x;
  if (n >= N) return;
  const float4* ip = (const float4*)(agg + (size_t)n * 16);
  float4 v[4];
  float m = -1e30f;
#pragma unroll
  for (int i = 0; i < 4; i++) {
    v[i] = ip[i];
    m = fmaxf(m, fmaxf(fmaxf(v[i].x, v[i].y), fmaxf(v[i].z, v[i].w)));
  }
  float ssum = 0.f;
#pragma unroll
  for (int i = 0; i < 4; i++) {
    ssum += expf(v[i].x - m) + expf(v[i].y - m) + expf(v[i].z - m) + expf(v[i].w - m);
  }
  float lse = m + logf(ssum);
  float4* op = (float4*)(out + (size_t)n * 16);
#pragma unroll
  for (int i = 0; i < 4; i++) {
    op[i] = make_float4(v[i].x - lse, v[i].y - lse, v[i].z - lse, v[i].w - lse);
  }
}

extern "C" void kernel_launch(void* const* d_in, const int* in_sizes, int n_in,
                              void* d_out, int out_size, void* d_ws, size_t ws_size,
                              hipStream_t stream) {
  const float* x = (const float*)d_in[0];
  const int* ei = (const int*)d_in[1];  // int32 (harness-converted from int64)
  const float* W1 = (const float*)d_in[2];
  const float* b1 = (const float*)d_in[3];
  const float* W2 = (const float*)d_in[4];
  const float* b2 = (const float*)d_in[5];
  float* out = (float*)d_out;

  const int N = in_sizes[0] / 64;
  const int E = in_sizes[1] / 2;
  const int Et = E + N;

  // Workspace layout (~54 MB). Layer-2 buffers alias the dead h1 region.
  char* ws = (char*)d_ws;
  float* h1 = (float*)ws;   ws += (size_t)N * 64 * 4;  // 25.6 MB
  float* agg1 = (float*)ws; ws += (size_t)N * 64 * 4;  // 25.6 MB
  int* deg = (int*)ws;      ws += (size_t)N * 4;       // deg,pos contiguous: one zero pass
  int* pos = (int*)ws;      ws += (size_t)N * 4;
  unsigned char* flags = (unsigned char*)ws;           // Et bytes
  float* h2 = h1;                                      // alias: h1 dead after layer-1 scatter
  float* agg2 = h1 + (size_t)N * 16;

  const int B = 256;

  // ---- layer 1 (D=64) ----
  hipLaunchKernelGGL((gemm_k<64, false>), dim3((N + B - 1) / B), dim3(B), 0, stream,
                     x, W1, h1, N);
  hipLaunchKernelGGL(zero_i32, dim3((2 * N + B - 1) / B), dim3(B), 0, stream, deg, 2 * N);
  hipLaunchKernelGGL((init_bias_k<64>), dim3((N * 64 + B - 1) / B), dim3(B), 0, stream,
                     agg1, b1, N);
  hipLaunchKernelGGL((edge_alpha_k<64, true>), dim3((Et + B - 1) / B), dim3(B), 0, stream,
                     ei, h1, flags, pos, deg, E, N);
  {
    long long tot = (long long)Et * 16;
    hipLaunchKernelGGL((edge_scatter_k<64>), dim3((unsigned)((tot + B - 1) / B)), dim3(B), 0,
                       stream, ei, h1, flags, pos, deg, agg1, E, N);
  }

  // ---- layer 2 (D=16), relu folded into GEMM load ----
  hipLaunchKernelGGL((gemm_k<16, true>), dim3((N + B - 1) / B), dim3(B), 0, stream,
                     agg1, W2, h2, N);
  hipLaunchKernelGGL(zero_i32, dim3((N + B - 1) / B), dim3(B), 0, stream, pos, N);
  hipLaunchKernelGGL((init_bias_k<16>), dim3((N * 16 + B - 1) / B), dim3(B), 0, stream,
                     agg2, b2, N);
  hipLaunchKernelGGL((edge_alpha_k<16, false>), dim3((Et + B - 1) / B), dim3(B), 0, stream,
                     ei, h2, flags, pos, deg, E, N);
  {
    long long tot = (long long)Et * 4;
    hipLaunchKernelGGL((edge_scatter_k<16>), dim3((unsigned)((tot + B - 1) / B)), dim3(B), 0,
                       stream, ei, h2, flags, pos, deg, agg2, E, N);
  }

  hipLaunchKernelGGL(logsoftmax16_k, dim3((N + B - 1) / B), dim3(B), 0, stream,
                     agg2, out, N);
}

// Round 3
// 843.110 us; speedup vs baseline: 2.7782x; 2.7782x over previous
//
#include <hip/hip_runtime.h>

// GAT (2-layer) on MI355X — CSR-gather formulation (no fp32 atomics).
// Closed-form segment softmax: alpha in {+t,-t}; per-src: p = #pos, deg = out-deg.
// p>0: w = (flag?1:e^{-2t}) / (p + (deg-p)e^{-2t});  p==0: w = 1/deg.
// edge_index arrives as int32 (harness converts integer inputs).
#define EXP_NEG2T 0.13533528323661270f  // exp(-2*1.0)

__global__ void zero_i32(int* __restrict__ p, int n) {
  int i = blockIdx.x * blockDim.x + threadIdx.x;
  if (i < n) p[i] = 0;
}

// h[N, DOUT] = (RELU_IN ? relu(x) : x)[N,64] @ W[DOUT,64]^T; W staged in LDS.
template <int DOUT, bool RELU_IN>
__global__ void gemm_k(const float* __restrict__ x, const float* __restrict__ W,
                       float* __restrict__ h, int N) {
  __shared__ float Wl[DOUT * 64];
  for (int i = threadIdx.x; i < DOUT * 64; i += 256) Wl[i] = W[i];
  __syncthreads();
  int row = blockIdx.x * 256 + threadIdx.x;
  if (row >= N) return;
  const float4* xp = (const float4*)(x + (size_t)row * 64);
  float4 xr[16];
#pragma unroll
  for (int i = 0; i < 16; i++) {
    float4 v = xp[i];
    if (RELU_IN) {
      v.x = fmaxf(v.x, 0.f); v.y = fmaxf(v.y, 0.f);
      v.z = fmaxf(v.z, 0.f); v.w = fmaxf(v.w, 0.f);
    }
    xr[i] = v;
  }
  float* hp = h + (size_t)row * DOUT;
  for (int d = 0; d < DOUT; d++) {
    const float4* wp = (const float4*)(Wl + d * 64);
    float acc = 0.f;
#pragma unroll
    for (int i = 0; i < 16; i++) {
      float4 w = wp[i];
      acc = fmaf(xr[i].x, w.x, acc);
      acc = fmaf(xr[i].y, w.y, acc);
      acc = fmaf(xr[i].z, w.z, acc);
      acc = fmaf(xr[i].w, w.w, acc);
    }
    hp[d] = acc;
  }
}

// Per edge (incl. N appended self-loops): sign of dot(h[dst],h[src]) -> flag;
// histogram pos[src]; on layer 1 also deg[src] (out) and in_deg[dst] (CSR).
template <int D, bool COUNT_DEG>
__global__ void edge_alpha_k(const int* __restrict__ ei, const float* __restrict__ h,
                             unsigned char* __restrict__ flags, int* __restrict__ pos,
                             int* __restrict__ deg, int* __restrict__ in_deg,
                             int E, int N) {
  int e = blockIdx.x * blockDim.x + threadIdx.x;
  if (e >= E + N) return;
  int s, d;
  if (e < E) { s = ei[e]; d = ei[E + e]; }
  else       { s = e - E; d = s; }
  const float4* hs = (const float4*)(h + (size_t)s * D);
  const float4* hd = (const float4*)(h + (size_t)d * D);
  float acc = 0.f;
#pragma unroll
  for (int i = 0; i < D / 4; i++) {
    float4 a = hs[i], b = hd[i];
    acc = fmaf(a.x, b.x, fmaf(a.y, b.y, fmaf(a.z, b.z, fmaf(a.w, b.w, acc))));
  }
  bool p = acc > 0.f;
  flags[e] = (unsigned char)p;
  if (p) atomicAdd(pos + s, 1);
  if (COUNT_DEG) {
    atomicAdd(deg + s, 1);
    atomicAdd(in_deg + d, 1);
  }
}

// ---- 3-kernel exclusive scan over in_deg[N] (N <= 512*256) ----
__global__ void scan_reduce_k(const int* __restrict__ v, int* __restrict__ part, int n) {
  __shared__ int l[256];
  int i = blockIdx.x * 256 + threadIdx.x;
  l[threadIdx.x] = (i < n) ? v[i] : 0;
  __syncthreads();
  for (int o = 128; o > 0; o >>= 1) {
    if (threadIdx.x < o) l[threadIdx.x] += l[threadIdx.x + o];
    __syncthreads();
  }
  if (threadIdx.x == 0) part[blockIdx.x] = l[0];
}

__global__ void scan_part_k(int* __restrict__ part, int nb) {  // 1 block, 512 thr
  __shared__ int l[512];
  int t = threadIdx.x;
  int v = (t < nb) ? part[t] : 0;
  l[t] = v;
  __syncthreads();
  for (int o = 1; o < 512; o <<= 1) {
    int a = (t >= o) ? l[t - o] : 0;
    __syncthreads();
    l[t] += a;
    __syncthreads();
  }
  if (t < nb) part[t] = l[t] - v;  // exclusive
}

__global__ void scan_final_k(const int* __restrict__ v, const int* __restrict__ part,
                             int* __restrict__ off, int n) {
  __shared__ int l[256];
  int t = threadIdx.x;
  int i = blockIdx.x * 256 + t;
  int x = (i < n) ? v[i] : 0;
  l[t] = x;
  __syncthreads();
  for (int o = 1; o < 256; o <<= 1) {
    int a = (t >= o) ? l[t - o] : 0;
    __syncthreads();
    l[t] += a;
    __syncthreads();
  }
  if (i < n) off[i] = l[t] - x + part[blockIdx.x];
}

// Per edge: compute closed-form weight, claim a slot in dst's CSR bucket,
// store (src, w) as int2. Sum order within a bucket is irrelevant.
__global__ void fill_k(const int* __restrict__ ei, const unsigned char* __restrict__ flags,
                       const int* __restrict__ pos, const int* __restrict__ deg,
                       const int* __restrict__ off, int* __restrict__ cnt,
                       int2* __restrict__ csr, int E, int N) {
  int e = blockIdx.x * blockDim.x + threadIdx.x;
  if (e >= E + N) return;
  int s, d;
  if (e < E) { s = ei[e]; d = ei[E + e]; }
  else       { s = e - E; d = s; }
  int p = pos[s], dg = deg[s];
  float w;
  if (p > 0) {
    float denom = (float)p + (float)(dg - p) * EXP_NEG2T;
    w = (flags[e] ? 1.0f : EXP_NEG2T) / denom;
  } else {
    w = 1.0f / (float)dg;
  }
  int slot = off[d] + atomicAdd(cnt + d, 1);
  csr[slot] = make_int2(s, __float_as_int(w));
}

// Gather: G = D/4 lanes per dst node, lane c owns float4 chunk c.
// acc starts at bias; each row written exactly once (no atomics).
// FUSE_LSM (D=16 only): 4-lane shfl_xor log-softmax, write final output.
template <int D, bool FUSE_LSM>
__global__ void gather_k(const int2* __restrict__ csr, const int* __restrict__ off,
                         const int* __restrict__ indeg, const float* __restrict__ h,
                         const float* __restrict__ b, float* __restrict__ outp, int N) {
  const int G = D / 4;
  int t = blockIdx.x * 256 + threadIdx.x;
  int node = t / G;
  int c = t & (G - 1);
  if (node >= N) return;
  const float4 bv = *(const float4*)(b + c * 4);
  float4 acc = bv;
  int j = off[node];
  int jend = j + indeg[node];
  for (; j < jend; ++j) {
    int2 sw = csr[j];
    float w = __int_as_float(sw.y);
    float4 hv = *(const float4*)(h + (size_t)sw.x * D + c * 4);
    acc.x = fmaf(w, hv.x, acc.x);
    acc.y = fmaf(w, hv.y, acc.y);
    acc.z = fmaf(w, hv.z, acc.z);
    acc.w = fmaf(w, hv.w, acc.w);
  }
  if (FUSE_LSM) {
    // 16 channels live in a 4-lane group (4 per lane): log-softmax in-register.
    float m = fmaxf(fmaxf(acc.x, acc.y), fmaxf(acc.z, acc.w));
    m = fmaxf(m, __shfl_xor(m, 1));
    m = fmaxf(m, __shfl_xor(m, 2));
    float s = expf(acc.x - m) + expf(acc.y - m) + expf(acc.z - m) + expf(acc.w - m);
    s += __shfl_xor(s, 1);
    s += __shfl_xor(s, 2);
    float lse = m + logf(s);
    acc.x -= lse; acc.y -= lse; acc.z -= lse; acc.w -= lse;
  }
  *(float4*)(outp + (size_t)node * D + c * 4) = acc;
}

extern "C" void kernel_launch(void* const* d_in, const int* in_sizes, int n_in,
                              void* d_out, int out_size, void* d_ws, size_t ws_size,
                              hipStream_t stream) {
  const float* x = (const float*)d_in[0];
  const int* ei = (const int*)d_in[1];
  const float* W1 = (const float*)d_in[2];
  const float* b1 = (const float*)d_in[3];
  const float* W2 = (const float*)d_in[4];
  const float* b2 = (const float*)d_in[5];
  float* out = (float*)d_out;

  const int N = in_sizes[0] / 64;
  const int E = in_sizes[1] / 2;
  const int Et = E + N;
  const int B = 256;
  const int nbN = (N + B - 1) / B;  // 391 for N=100k (scan assumes nbN <= 512)
  const int nbE = (Et + B - 1) / B;

  // Workspace (~69 MB): layer-2 buffers alias dead h1 region.
  char* ws = (char*)d_ws;
  float* h1 = (float*)ws;    ws += (size_t)N * 64 * 4;   // 25.6 MB
  float* agg1 = (float*)ws;  ws += (size_t)N * 64 * 4;   // 25.6 MB
  int* deg = (int*)ws;       ws += (size_t)N * 4;        // [deg|in_deg|pos|cnt] contiguous
  int* in_deg = (int*)ws;    ws += (size_t)N * 4;
  int* pos = (int*)ws;       ws += (size_t)N * 4;
  int* cnt = (int*)ws;       ws += (size_t)N * 4;
  int* off = (int*)ws;       ws += (size_t)N * 4;
  int* part = (int*)ws;      ws += 512 * 4;
  unsigned char* flags = (unsigned char*)ws; ws += ((size_t)Et + 255) & ~255ull;
  int2* csr = (int2*)ws;     ws += (size_t)Et * 8;       // 13.6 MB
  float* h2 = h1;            // alias: h1 dead after gather1
  float* h2_end = h1 + (size_t)N * 16; (void)h2_end;

  // ---- layer 1 (D=64) ----
  hipLaunchKernelGGL(zero_i32, dim3((4 * N + B - 1) / B), dim3(B), 0, stream, deg, 4 * N);
  hipLaunchKernelGGL((gemm_k<64, false>), dim3(nbN), dim3(B), 0, stream, x, W1, h1, N);
  hipLaunchKernelGGL((edge_alpha_k<64, true>), dim3(nbE), dim3(B), 0, stream,
                     ei, h1, flags, pos, deg, in_deg, E, N);
  // CSR structure (once; reused by both layers)
  hipLaunchKernelGGL(scan_reduce_k, dim3(nbN), dim3(B), 0, stream, in_deg, part, N);
  hipLaunchKernelGGL(scan_part_k, dim3(1), dim3(512), 0, stream, part, nbN);
  hipLaunchKernelGGL(scan_final_k, dim3(nbN), dim3(B), 0, stream, in_deg, part, off, N);
  hipLaunchKernelGGL(fill_k, dim3(nbE), dim3(B), 0, stream,
                     ei, flags, pos, deg, off, cnt, csr, E, N);
  hipLaunchKernelGGL((gather_k<64, false>), dim3(((size_t)N * 16 + B - 1) / B), dim3(B), 0,
                     stream, csr, off, in_deg, h1, b1, agg1, N);

  // ---- layer 2 (D=16): relu folded into gemm load, log-softmax fused ----
  hipLaunchKernelGGL(zero_i32, dim3((2 * N + B - 1) / B), dim3(B), 0, stream, pos, 2 * N);
  hipLaunchKernelGGL((gemm_k<16, true>), dim3(nbN), dim3(B), 0, stream, agg1, W2, h2, N);
  hipLaunchKernelGGL((edge_alpha_k<16, false>), dim3(nbE), dim3(B), 0, stream,
                     ei, h2, flags, pos, deg, in_deg, E, N);
  hipLaunchKernelGGL(fill_k, dim3(nbE), dim3(B), 0, stream,
                     ei, flags, pos, deg, off, cnt, csr, E, N);
  hipLaunchKernelGGL((gather_k<16, true>), dim3(((size_t)N * 4 + B - 1) / B), dim3(B), 0,
                     stream, csr, off, in_deg, h2, b2, out, N);
}

// Round 4
// 821.850 us; speedup vs baseline: 2.8500x; 1.0259x over previous
//
#include <hip/hip_runtime.h>

// GAT (2-layer) on MI355X — full-CSR formulation, cooperative row reads.
// Closed-form segment softmax: alpha in {+t,-t}; per-src s: p=#pos out-edges,
// deg=out-degree (incl self-loop).
//   p>0: w = (flag?1:c)/(p+(deg-p)c)   p==0: w = 1/deg = c * (1/(c*deg))
// -> w = (flag?1:c) * dinv[s],  dinv = p>0 ? 1/(p+(deg-p)c) : 1/(c*deg).
// edge_index arrives as int32 (harness converts integer inputs).
#define EXPC 0.13533528323661270f  // exp(-2*1.0)

__global__ void zero_i32(int* __restrict__ p, int n) {
  int i = blockIdx.x * blockDim.x + threadIdx.x;
  if (i < n) p[i] = 0;
}

// h[N, DOUT] = (RELU_IN ? relu(x) : x)[N,64] @ W[DOUT,64]^T; W staged in LDS.
template <int DOUT, bool RELU_IN>
__global__ void gemm_k(const float* __restrict__ x, const float* __restrict__ W,
                       float* __restrict__ h, int N) {
  __shared__ float Wl[DOUT * 64];
  for (int i = threadIdx.x; i < DOUT * 64; i += 256) Wl[i] = W[i];
  __syncthreads();
  int row = blockIdx.x * 256 + threadIdx.x;
  if (row >= N) return;
  const float4* xp = (const float4*)(x + (size_t)row * 64);
  float4 xr[16];
#pragma unroll
  for (int i = 0; i < 16; i++) {
    float4 v = xp[i];
    if (RELU_IN) {
      v.x = fmaxf(v.x, 0.f); v.y = fmaxf(v.y, 0.f);
      v.z = fmaxf(v.z, 0.f); v.w = fmaxf(v.w, 0.f);
    }
    xr[i] = v;
  }
  float* hp = h + (size_t)row * DOUT;
  for (int d = 0; d < DOUT; d++) {
    const float4* wp = (const float4*)(Wl + d * 64);
    float acc = 0.f;
#pragma unroll
    for (int i = 0; i < 16; i++) {
      float4 w = wp[i];
      acc = fmaf(xr[i].x, w.x, acc);
      acc = fmaf(xr[i].y, w.y, acc);
      acc = fmaf(xr[i].z, w.z, acc);
      acc = fmaf(xr[i].w, w.w, acc);
    }
    hp[d] = acc;
  }
}

// Degree histograms over edges + self-loops (structure only, data-independent).
__global__ void hist_k(const int* __restrict__ ei, int* __restrict__ deg,
                       int* __restrict__ in_deg, int E, int N) {
  int e = blockIdx.x * blockDim.x + threadIdx.x;
  if (e >= E + N) return;
  int s, d;
  if (e < E) { s = ei[e]; d = ei[E + e]; }
  else       { s = e - E; d = s; }
  atomicAdd(deg + s, 1);
  atomicAdd(in_deg + d, 1);
}

// ---- 3-kernel exclusive scan over in_deg[N] (nbN <= 512) ----
__global__ void scan_reduce_k(const int* __restrict__ v, int* __restrict__ part, int n) {
  __shared__ int l[256];
  int i = blockIdx.x * 256 + threadIdx.x;
  l[threadIdx.x] = (i < n) ? v[i] : 0;
  __syncthreads();
  for (int o = 128; o > 0; o >>= 1) {
    if (threadIdx.x < o) l[threadIdx.x] += l[threadIdx.x + o];
    __syncthreads();
  }
  if (threadIdx.x == 0) part[blockIdx.x] = l[0];
}

__global__ void scan_part_k(int* __restrict__ part, int nb) {  // 1 block, 512 thr
  __shared__ int l[512];
  int t = threadIdx.x;
  int v = (t < nb) ? part[t] : 0;
  l[t] = v;
  __syncthreads();
  for (int o = 1; o < 512; o <<= 1) {
    int a = (t >= o) ? l[t - o] : 0;
    __syncthreads();
    l[t] += a;
    __syncthreads();
  }
  if (t < nb) part[t] = l[t] - v;  // exclusive
}

__global__ void scan_final_k(const int* __restrict__ v, const int* __restrict__ part,
                             int* __restrict__ off, int n) {
  __shared__ int l[256];
  int t = threadIdx.x;
  int i = blockIdx.x * 256 + t;
  int x = (i < n) ? v[i] : 0;
  l[t] = x;
  __syncthreads();
  for (int o = 1; o < 256; o <<= 1) {
    int a = (t >= o) ? l[t - o] : 0;
    __syncthreads();
    l[t] += a;
    __syncthreads();
  }
  if (i < n) off[i] = l[t] - x + part[blockIdx.x];
}

// Per edge: claim slot in dst's bucket, store src. Bucket order irrelevant.
__global__ void fill_struct_k(const int* __restrict__ ei, const int* __restrict__ off,
                              int* __restrict__ cnt, int* __restrict__ csr_src,
                              int E, int N) {
  int e = blockIdx.x * blockDim.x + threadIdx.x;
  if (e >= E + N) return;
  int s, d;
  if (e < E) { s = ei[e]; d = ei[E + e]; }
  else       { s = e - E; d = s; }
  csr_src[off[d] + atomicAdd(cnt + d, 1)] = s;
}

// Alpha pass over CSR: G=D/4 lanes per dst node; lane c holds h[dst] chunk c.
// Per in-edge: coalesced 256B (64B) read of h[src], dot via shfl_xor reduce,
// sign -> flag per CSR slot, histogram pos[src].
template <int D>
__global__ void alpha_csr_k(const int* __restrict__ csr_src, const int* __restrict__ off,
                            const int* __restrict__ indeg, const float* __restrict__ h,
                            unsigned char* __restrict__ flagb, int* __restrict__ pos, int N) {
  const int G = D / 4;
  int t = blockIdx.x * 256 + threadIdx.x;
  int node = t / G;
  int c = t & (G - 1);
  if (node >= N) return;
  const float4 hd = *(const float4*)(h + (size_t)node * D + c * 4);
  int j = off[node];
  int je = j + indeg[node];
  for (; j < je; ++j) {
    int s = csr_src[j];  // same addr across G lanes -> broadcast
    float4 hs = *(const float4*)(h + (size_t)s * D + c * 4);
    float p = fmaf(hs.x, hd.x, fmaf(hs.y, hd.y, fmaf(hs.z, hd.z, hs.w * hd.w)));
#pragma unroll
    for (int o = G / 2; o > 0; o >>= 1) p += __shfl_xor(p, o);
    if (c == 0) {
      bool pz = p > 0.f;
      flagb[j] = (unsigned char)pz;
      if (pz) atomicAdd(pos + s, 1);
    }
  }
}

__global__ void denom_k(const int* __restrict__ pos, const int* __restrict__ deg,
                        float* __restrict__ dinv, int N) {
  int i = blockIdx.x * blockDim.x + threadIdx.x;
  if (i >= N) return;
  int p = pos[i], dg = deg[i];
  dinv[i] = (p > 0) ? 1.f / ((float)p + (float)(dg - p) * EXPC)
                    : 1.f / (EXPC * (float)dg);
}

// Gather over CSR: G=D/4 lanes per node; acc starts at bias; one write per row.
// FUSE_LSM (D=16): 4-lane log-softmax in-register, writes final output.
template <int D, bool FUSE_LSM>
__global__ void gather_csr_k(const int* __restrict__ csr_src, const int* __restrict__ off,
                             const int* __restrict__ indeg,
                             const unsigned char* __restrict__ flagb,
                             const float* __restrict__ dinv, const float* __restrict__ h,
                             const float* __restrict__ b, float* __restrict__ outp, int N) {
  const int G = D / 4;
  int t = blockIdx.x * 256 + threadIdx.x;
  int node = t / G;
  int c = t & (G - 1);
  if (node >= N) return;
  float4 acc = *(const float4*)(b + c * 4);
  int j = off[node];
  int je = j + indeg[node];
  for (; j < je; ++j) {
    int s = csr_src[j];
    float w = (flagb[j] ? 1.f : EXPC) * dinv[s];
    float4 hv = *(const float4*)(h + (size_t)s * D + c * 4);
    acc.x = fmaf(w, hv.x, acc.x);
    acc.y = fmaf(w, hv.y, acc.y);
    acc.z = fmaf(w, hv.z, acc.z);
    acc.w = fmaf(w, hv.w, acc.w);
  }
  if (FUSE_LSM) {
    float m = fmaxf(fmaxf(acc.x, acc.y), fmaxf(acc.z, acc.w));
    m = fmaxf(m, __shfl_xor(m, 1));
    m = fmaxf(m, __shfl_xor(m, 2));
    float s = expf(acc.x - m) + expf(acc.y - m) + expf(acc.z - m) + expf(acc.w - m);
    s += __shfl_xor(s, 1);
    s += __shfl_xor(s, 2);
    float lse = m + logf(s);
    acc.x -= lse; acc.y -= lse; acc.z -= lse; acc.w -= lse;
  }
  *(float4*)(outp + (size_t)node * D + c * 4) = acc;
}

extern "C" void kernel_launch(void* const* d_in, const int* in_sizes, int n_in,
                              void* d_out, int out_size, void* d_ws, size_t ws_size,
                              hipStream_t stream) {
  const float* x = (const float*)d_in[0];
  const int* ei = (const int*)d_in[1];
  const float* W1 = (const float*)d_in[2];
  const float* b1 = (const float*)d_in[3];
  const float* W2 = (const float*)d_in[4];
  const float* b2 = (const float*)d_in[5];
  float* out = (float*)d_out;

  const int N = in_sizes[0] / 64;
  const int E = in_sizes[1] / 2;
  const int Et = E + N;
  const int B = 256;
  const int nbN = (N + B - 1) / B;  // 391 for N=100k; scan assumes <=512
  const int nbE = (Et + B - 1) / B;

  // Workspace (~63 MB).
  char* ws = (char*)d_ws;
  float* h1 = (float*)ws;      ws += (size_t)N * 64 * 4;  // 25.6 MB
  float* agg1 = (float*)ws;    ws += (size_t)N * 64 * 4;  // 25.6 MB
  int* deg = (int*)ws;         ws += (size_t)N * 4;       // [deg|in_deg|pos|cnt]
  int* in_deg = (int*)ws;      ws += (size_t)N * 4;
  int* pos = (int*)ws;         ws += (size_t)N * 4;
  int* cnt = (int*)ws;         ws += (size_t)N * 4;
  int* off = (int*)ws;         ws += (size_t)N * 4;
  float* dinv = (float*)ws;    ws += (size_t)N * 4;
  int* part = (int*)ws;        ws += 512 * 4;
  int* csr_src = (int*)ws;     ws += (size_t)Et * 4;      // 6.8 MB
  unsigned char* flagb = (unsigned char*)ws; ws += (size_t)Et;
  float* h2 = h1;  // alias: h1 dead once gather1 completes

  // ---- CSR structure (data-independent, built once) ----
  hipLaunchKernelGGL(zero_i32, dim3((4 * N + B - 1) / B), dim3(B), 0, stream, deg, 4 * N);
  hipLaunchKernelGGL(hist_k, dim3(nbE), dim3(B), 0, stream, ei, deg, in_deg, E, N);
  hipLaunchKernelGGL(scan_reduce_k, dim3(nbN), dim3(B), 0, stream, in_deg, part, N);
  hipLaunchKernelGGL(scan_part_k, dim3(1), dim3(512), 0, stream, part, nbN);
  hipLaunchKernelGGL(scan_final_k, dim3(nbN), dim3(B), 0, stream, in_deg, part, off, N);
  hipLaunchKernelGGL(fill_struct_k, dim3(nbE), dim3(B), 0, stream, ei, off, cnt, csr_src, E, N);

  // ---- layer 1 (D=64) ----
  hipLaunchKernelGGL((gemm_k<64, false>), dim3(nbN), dim3(B), 0, stream, x, W1, h1, N);
  hipLaunchKernelGGL((alpha_csr_k<64>), dim3(((size_t)N * 16 + B - 1) / B), dim3(B), 0,
                     stream, csr_src, off, in_deg, h1, flagb, pos, N);
  hipLaunchKernelGGL(denom_k, dim3(nbN), dim3(B), 0, stream, pos, deg, dinv, N);
  hipLaunchKernelGGL((gather_csr_k<64, false>), dim3(((size_t)N * 16 + B - 1) / B), dim3(B),
                     0, stream, csr_src, off, in_deg, flagb, dinv, h1, b1, agg1, N);

  // ---- layer 2 (D=16): relu folded into gemm load, log-softmax fused ----
  hipLaunchKernelGGL(zero_i32, dim3(nbN), dim3(B), 0, stream, pos, N);
  hipLaunchKernelGGL((gemm_k<16, true>), dim3(nbN), dim3(B), 0, stream, agg1, W2, h2, N);
  hipLaunchKernelGGL((alpha_csr_k<16>), dim3(((size_t)N * 4 + B - 1) / B), dim3(B), 0,
                     stream, csr_src, off, in_deg, h2, flagb, pos, N);
  hipLaunchKernelGGL(denom_k, dim3(nbN), dim3(B), 0, stream, pos, deg, dinv, N);
  hipLaunchKernelGGL((gather_csr_k<16, true>), dim3(((size_t)N * 4 + B - 1) / B), dim3(B),
                     0, stream, csr_src, off, in_deg, flagb, dinv, h2, b2, out, N);
}